// Round 2
// baseline (174.711 us; speedup 1.0000x reference)
//
#include <hip/hip_runtime.h>
#include <math.h>

#define NCLS 20
#define CH 64
#define NPIX (384*384)
#define BATCH 2
#define MINSZ 5000
#define EPSV 1e-6f
#define NCHUNK 24
#define NBLK (BATCH*NPIX/256)      // 1152
#define BLKPERB (NPIX/256)         // 576
#define PSTRIDE 4160               // 4096 sxx + 64 sums

// ---------------- K1: per-block class histogram ----------------
__global__ void k_hist(const int* __restrict__ seg, int* __restrict__ hist) {
    __shared__ int h[NCLS];
    int t = threadIdx.x;
    if (t < NCLS) h[t] = 0;
    __syncthreads();
    int k = seg[blockIdx.x * 256 + t];
    atomicAdd(&h[k], 1);
    __syncthreads();
    if (t < NCLS) hist[blockIdx.x * NCLS + t] = h[t];
}

// ---------------- K2a: per-(b,k) counts ----------------
__global__ void k_counts(const int* __restrict__ hist, int* __restrict__ counts) {
    int bk = blockIdx.x;
    int b = bk / NCLS, k = bk % NCLS;
    __shared__ int sred[256];
    int t = threadIdx.x;
    int s = 0;
    for (int e = t; e < BLKPERB; e += 256) s += hist[(b*BLKPERB + e)*NCLS + k];
    sred[t] = s;
    __syncthreads();
    for (int st = 128; st > 0; st >>= 1) {
        if (t < st) sred[t] += sred[t + st];
        __syncthreads();
    }
    if (t == 0) counts[bk] = sred[0];
}

// ---------------- K2b: per-(b,k) exclusive scan over blocks ----------------
__global__ void k_scan(const int* __restrict__ hist, const int* __restrict__ counts,
                       int* __restrict__ blockbase, int* __restrict__ offsets) {
    int bk = blockIdx.x;
    int b = bk / NCLS;
    int k = bk % NCLS;
    __shared__ int sh[BLKPERB];
    int t = threadIdx.x;
    for (int e = t; e < BLKPERB; e += 256) sh[e] = hist[(b*BLKPERB + e)*NCLS + k];
    __syncthreads();
    if (t == 0) {
        int off = b * NPIX;
        for (int kk = b*NCLS; kk < bk; ++kk) off += counts[kk];
        offsets[bk] = off;
        int run = off;
        #pragma unroll 8
        for (int e = 0; e < BLKPERB; ++e) { int v = sh[e]; sh[e] = run; run += v; }
    }
    __syncthreads();
    for (int e = t; e < BLKPERB; e += 256) blockbase[(b*BLKPERB + e)*NCLS + k] = sh[e];
}

// ---------------- K3: stable scatter into pixel-major gathered buffer ----------------
__global__ void k_scatter(const float* __restrict__ x, const int* __restrict__ seg,
                          const int* __restrict__ blockbase, float* __restrict__ gathered) {
    __shared__ int sseg[256];
    int t = threadIdx.x;
    int blk = blockIdx.x;
    int base = blk * 256;            // global pixel id over B*N
    int b = base / NPIX;
    int n = (base % NPIX) + t;       // pixel within batch
    int k = seg[base + t];
    sseg[t] = k;
    __syncthreads();
    int rank = 0;
    for (int j = 0; j < 256; ++j) {
        if (j < t && sseg[j] == k) rank++;
    }
    int pos = blockbase[blk*NCLS + k] + rank;   // unique, deterministic
    const float* xb = x + (size_t)b * CH * NPIX + n;
    float4* dst = (float4*)(gathered + (size_t)pos * CH);
    #pragma unroll
    for (int q = 0; q < 16; ++q) {
        float4 v;
        v.x = xb[(size_t)(4*q+0) * NPIX];
        v.y = xb[(size_t)(4*q+1) * NPIX];
        v.z = xb[(size_t)(4*q+2) * NPIX];
        v.w = xb[(size_t)(4*q+3) * NPIX];
        dst[q] = v;
    }
}

// ---------------- K4: per-(b,k,chunk) rank-n update (sxx partials + sums) ----------------
__global__ void __launch_bounds__(256) k_gemm(const float* __restrict__ gathered,
        const int* __restrict__ counts, const int* __restrict__ offsets,
        float* __restrict__ partials) {
    __shared__ float xs[64][CH];     // 64 pixels x 64 channels, 16 KB
    int id = blockIdx.x;
    int chunk = id % NCHUNK;
    int bk = id / NCHUNK;
    int cnt = counts[bk];
    int off = offsets[bk];
    int csz = (cnt + NCHUNK - 1) / NCHUNK;
    int p0 = chunk * csz;
    int p1 = min(cnt, p0 + csz);
    int t = threadIdx.x;
    int tx = t & 15, ty = t >> 4;
    float acc[4][4] = {{0.f}};
    float sloc = 0.f;                // channel-sum for channel t (t<64)

    for (int p = p0; p < p1; p += 64) {
        __syncthreads();             // protect xs from previous tile's readers
        #pragma unroll
        for (int i = 0; i < 4; ++i) {
            int f = i * 256 + t;     // float4 id 0..1023
            int px = f >> 4;
            int c4 = (f & 15) << 2;
            float4 v = make_float4(0.f, 0.f, 0.f, 0.f);
            if (p + px < p1)
                v = *(const float4*)(gathered + (size_t)(off + p + px) * CH + c4);
            *(float4*)(&xs[px][c4]) = v;
        }
        __syncthreads();
        #pragma unroll 4
        for (int pp = 0; pp < 64; ++pp) {
            float4 av = *(const float4*)(&xs[pp][ty << 2]);
            float4 bv = *(const float4*)(&xs[pp][tx << 2]);
            acc[0][0] += av.x*bv.x; acc[0][1] += av.x*bv.y; acc[0][2] += av.x*bv.z; acc[0][3] += av.x*bv.w;
            acc[1][0] += av.y*bv.x; acc[1][1] += av.y*bv.y; acc[1][2] += av.y*bv.z; acc[1][3] += av.y*bv.w;
            acc[2][0] += av.z*bv.x; acc[2][1] += av.z*bv.y; acc[2][2] += av.z*bv.z; acc[2][3] += av.z*bv.w;
            acc[3][0] += av.w*bv.x; acc[3][1] += av.w*bv.y; acc[3][2] += av.w*bv.z; acc[3][3] += av.w*bv.w;
        }
        if (t < CH) {
            #pragma unroll 8
            for (int pp = 0; pp < 64; ++pp) sloc += xs[pp][t];
        }
    }

    float* pout = partials + (size_t)id * PSTRIDE;
    #pragma unroll
    for (int i = 0; i < 4; ++i) {
        float4 v = make_float4(acc[i][0], acc[i][1], acc[i][2], acc[i][3]);
        *(float4*)(pout + ((ty*4 + i) * 64 + tx*4)) = v;
    }
    if (t < CH) pout[4096 + t] = sloc;
}

// ---------------- K5: reduce partials, build cov, solve cov*w = p ----------------
__global__ void __launch_bounds__(256) k_solve(const float* __restrict__ partials,
        const int* __restrict__ counts, const float* __restrict__ pattern,
        float* __restrict__ params) {
    int bk = blockIdx.x;
    int t = threadIdx.x;
    __shared__ float M[64][66];      // augmented [cov | rhs@64]
    __shared__ float ssum[CH];
    __shared__ float wv[CH];
    __shared__ float red[2];

    const float* pp = partials + (size_t)bk * NCHUNK * PSTRIDE;
    for (int e = t; e < 4096; e += 256) {
        float v = 0.f;
        for (int ch = 0; ch < NCHUNK; ++ch) v += pp[(size_t)ch * PSTRIDE + e];
        M[e >> 6][e & 63] = v;       // sxx for now
    }
    if (t < CH) {
        float v = 0.f;
        for (int ch = 0; ch < NCHUNK; ++ch) v += pp[(size_t)ch * PSTRIDE + 4096 + t];
        ssum[t] = v;
    }
    __syncthreads();

    int cnt = counts[bk];
    float safe = fmaxf((float)cnt, 1.0f);
    float inv = 1.0f / safe;
    for (int e = t; e < 4096; e += 256) {
        int c = e >> 6, d = e & 63;
        float cov = M[c][d] * inv - (ssum[c] * inv) * (ssum[d] * inv);
        if (c == d) cov += EPSV;
        M[c][d] = cov;
    }
    if (t < CH) M[t][64] = pattern[t];
    __syncthreads();

    // forward elimination (SPD, no pivoting)
    int r = t >> 2, q = t & 3;
    for (int j = 0; j < 63; ++j) {
        if (r > j) {
            float f = M[r][j] / M[j][j];
            for (int d = j + 1 + q; d <= 64; d += 4) M[r][d] -= f * M[j][d];
        }
        __syncthreads();
    }
    // back substitution
    for (int j = 63; j >= 0; --j) {
        if (t == 0) wv[j] = M[j][64] / M[j][j];
        __syncthreads();
        if (t < j) M[t][64] -= M[t][j] * wv[j];
        __syncthreads();
    }

    if (t == 0) {
        float dp = 0.f, bias = 0.f;
        for (int c = 0; c < CH; ++c) {
            dp += pattern[c] * wv[c];
            bias += (ssum[c] * inv) * wv[c];
        }
        float denom = sqrtf(dp);
        float valid = (cnt >= MINSZ) ? 1.0f : 0.0f;
        float scale = (denom > 0.f) ? (valid / denom) : 0.0f;
        red[0] = scale;
        red[1] = bias * scale;
    }
    __syncthreads();
    if (t < CH) params[bk*66 + t] = wv[t] * red[0];
    if (t == 0) params[bk*66 + 64] = red[1];
    if (t == 1) params[bk*66 + 65] = 0.f;
}

// ---------------- K6: fused per-pixel score ----------------
__global__ void k_score(const float* __restrict__ x, const int* __restrict__ seg,
                        const float* __restrict__ params, float* __restrict__ out) {
    __shared__ float pw[NCLS][66];
    int t = threadIdx.x;
    int base = blockIdx.x * 256;
    int b = base / NPIX;
    for (int e = t; e < NCLS*66; e += 256)
        ((float*)pw)[e] = params[b*NCLS*66 + e];
    __syncthreads();

    int k = seg[base + t];
    int n = (base % NPIX) + t;
    const float* xb = x + (size_t)b * CH * NPIX + n;
    float a0 = 0.f, a1 = 0.f, a2 = 0.f, a3 = 0.f;
    #pragma unroll
    for (int c = 0; c < CH; c += 4) {
        a0 += xb[(size_t)(c+0) * NPIX] * pw[k][c+0];
        a1 += xb[(size_t)(c+1) * NPIX] * pw[k][c+1];
        a2 += xb[(size_t)(c+2) * NPIX] * pw[k][c+2];
        a3 += xb[(size_t)(c+3) * NPIX] * pw[k][c+3];
    }
    out[base + t] = (a0 + a1) + (a2 + a3) - pw[k][64];
}

// ---------------- launch ----------------
extern "C" void kernel_launch(void* const* d_in, const int* in_sizes, int n_in,
                              void* d_out, int out_size, void* d_ws, size_t ws_size,
                              hipStream_t stream) {
    const float* x       = (const float*)d_in[0];   // (B,C,H,W) fp32
    const float* pattern = (const float*)d_in[1];   // (C,) fp32
    const int*   seg     = (const int*)d_in[2];     // (B,H,W) int32
    float* out = (float*)d_out;

    float* wsf      = (float*)d_ws;
    float* gathered = wsf;                                             // B*N*CH
    float* partials = gathered + (size_t)BATCH * NPIX * CH;            // B*K*NCHUNK*PSTRIDE
    float* params   = partials + (size_t)BATCH * NCLS * NCHUNK * PSTRIDE; // B*K*66
    int* hist      = (int*)(params + BATCH * NCLS * 66);               // NBLK*NCLS
    int* blockbase = hist + NBLK * NCLS;                               // NBLK*NCLS
    int* counts    = blockbase + NBLK * NCLS;                          // B*K
    int* offsets   = counts + BATCH * NCLS;                            // B*K

    k_hist   <<<NBLK,               256, 0, stream>>>(seg, hist);
    k_counts <<<BATCH*NCLS,         256, 0, stream>>>(hist, counts);
    k_scan   <<<BATCH*NCLS,         256, 0, stream>>>(hist, counts, blockbase, offsets);
    k_scatter<<<NBLK,               256, 0, stream>>>(x, seg, blockbase, gathered);
    k_gemm   <<<BATCH*NCLS*NCHUNK,  256, 0, stream>>>(gathered, counts, offsets, partials);
    k_solve  <<<BATCH*NCLS,         256, 0, stream>>>(partials, counts, pattern, params);
    k_score  <<<NBLK,               256, 0, stream>>>(x, seg, params, out);
}

// Round 3
// 162.796 us; speedup vs baseline: 1.0732x; 1.0732x over previous
//
#include <hip/hip_runtime.h>
#include <math.h>

#define NCLS 20
#define CH 64
#define NPIX (384*384)
#define BATCH 2
#define MINSZ 5000
#define EPSV 1e-6f
#define NCHUNK 24
#define NBLK (BATCH*NPIX/256)      // 1152
#define BLKPERB (NPIX/256)         // 576
#define PSTRIDE 4160               // 4096 sxx + 64 sums

// ---------------- K1: per-block class histogram ----------------
__global__ void k_hist(const int* __restrict__ seg, int* __restrict__ hist) {
    __shared__ int h[NCLS];
    int t = threadIdx.x;
    if (t < NCLS) h[t] = 0;
    __syncthreads();
    int k = seg[blockIdx.x * 256 + t];
    atomicAdd(&h[k], 1);
    __syncthreads();
    if (t < NCLS) hist[blockIdx.x * NCLS + t] = h[t];
}

// ---------------- K2a: per-(b,k) counts ----------------
__global__ void k_counts(const int* __restrict__ hist, int* __restrict__ counts) {
    int bk = blockIdx.x;
    int b = bk / NCLS, k = bk % NCLS;
    __shared__ int sred[256];
    int t = threadIdx.x;
    int s = 0;
    for (int e = t; e < BLKPERB; e += 256) s += hist[(b*BLKPERB + e)*NCLS + k];
    sred[t] = s;
    __syncthreads();
    for (int st = 128; st > 0; st >>= 1) {
        if (t < st) sred[t] += sred[t + st];
        __syncthreads();
    }
    if (t == 0) counts[bk] = sred[0];
}

// ---------------- K2b: per-(b,k) exclusive scan over blocks ----------------
__global__ void k_scan(const int* __restrict__ hist, const int* __restrict__ counts,
                       int* __restrict__ blockbase, int* __restrict__ offsets) {
    int bk = blockIdx.x;
    int b = bk / NCLS;
    int k = bk % NCLS;
    __shared__ int sh[BLKPERB];
    int t = threadIdx.x;
    for (int e = t; e < BLKPERB; e += 256) sh[e] = hist[(b*BLKPERB + e)*NCLS + k];
    __syncthreads();
    if (t == 0) {
        int off = b * NPIX;
        for (int kk = b*NCLS; kk < bk; ++kk) off += counts[kk];
        offsets[bk] = off;
        int run = off;
        #pragma unroll 8
        for (int e = 0; e < BLKPERB; ++e) { int v = sh[e]; sh[e] = run; run += v; }
    }
    __syncthreads();
    for (int e = t; e < BLKPERB; e += 256) blockbase[(b*BLKPERB + e)*NCLS + k] = sh[e];
}

// ---------------- K3: LDS-staged class-sorted scatter (coalesced writes) ----------------
__global__ void __launch_bounds__(256) k_scatter(const float* __restrict__ x, const int* __restrict__ seg,
                          const int* __restrict__ blockbase, float* __restrict__ gathered) {
    __shared__ float tile[256 * 33];     // slot-major, stride 33 (pad) = 33 KB
    __shared__ int wcnt[4][NCLS];        // per-wave per-class counts
    __shared__ int sblk[NCLS];           // class start within block (sorted order)
    __shared__ int drow[256];            // dest row in `gathered` per sorted slot
    int t = threadIdx.x;
    int blk = blockIdx.x;
    int base = blk * 256;
    int b = base / NPIX;
    int n = (base % NPIX) + t;
    int k = seg[base + t];
    int wave = t >> 6, lane = t & 63;

    // deterministic stable rank via per-wave ballots
    int riw = 0;
    for (int cls = 0; cls < NCLS; ++cls) {
        unsigned long long m = __ballot(k == cls);
        if (lane == 0) wcnt[wave][cls] = __popcll(m);
        if (k == cls) riw = __popcll(m & ((1ull << lane) - 1ull));
    }
    __syncthreads();
    if (t < NCLS) {
        int s = 0;
        for (int c = 0; c < t; ++c) s += wcnt[0][c] + wcnt[1][c] + wcnt[2][c] + wcnt[3][c];
        sblk[t] = s;
    }
    __syncthreads();
    int rib = riw;
    for (int w = 0; w < 4; ++w) if (w < wave) rib += wcnt[w][k];
    int slot = sblk[k] + rib;            // sorted position within block (permutation of 0..255)
    drow[slot] = blockbase[blk * NCLS + k] + rib;
    const float* xb = x + (size_t)b * CH * NPIX + n;

    // two channel-phases of 32, so tile fits comfortably and all lanes stay active
    for (int ph = 0; ph < 2; ++ph) {
        __syncthreads();                 // protect tile + drow
        #pragma unroll 8
        for (int c = 0; c < 32; ++c)
            tile[slot * 33 + c] = xb[(size_t)(ph * 32 + c) * NPIX];
        __syncthreads();
        // copy out: rows in sorted order -> dest rows contiguous per class run
        #pragma unroll 8
        for (int it = 0; it < 32; ++it) {
            int f = it * 256 + t;
            int r = f >> 5, c = f & 31;
            gathered[(size_t)drow[r] * CH + ph * 32 + c] = tile[r * 33 + c];
        }
    }
}

// ---------------- K4: per-(b,k,chunk) rank-n update (sxx partials + sums) ----------------
__global__ void __launch_bounds__(256) k_gemm(const float* __restrict__ gathered,
        const int* __restrict__ counts, const int* __restrict__ offsets,
        float* __restrict__ partials) {
    __shared__ float xs[64][CH];     // 64 pixels x 64 channels, 16 KB
    int id = blockIdx.x;
    int chunk = id % NCHUNK;
    int bk = id / NCHUNK;
    int cnt = counts[bk];
    int off = offsets[bk];
    int csz = (cnt + NCHUNK - 1) / NCHUNK;
    int p0 = chunk * csz;
    int p1 = min(cnt, p0 + csz);
    int t = threadIdx.x;
    int tx = t & 15, ty = t >> 4;
    float acc[4][4] = {{0.f}};
    float sloc = 0.f;                // channel-sum for channel t (t<64)

    for (int p = p0; p < p1; p += 64) {
        __syncthreads();             // protect xs from previous tile's readers
        #pragma unroll
        for (int i = 0; i < 4; ++i) {
            int f = i * 256 + t;     // float4 id 0..1023
            int px = f >> 4;
            int c4 = (f & 15) << 2;
            float4 v = make_float4(0.f, 0.f, 0.f, 0.f);
            if (p + px < p1)
                v = *(const float4*)(gathered + (size_t)(off + p + px) * CH + c4);
            *(float4*)(&xs[px][c4]) = v;
        }
        __syncthreads();
        #pragma unroll 4
        for (int pp = 0; pp < 64; ++pp) {
            float4 av = *(const float4*)(&xs[pp][ty << 2]);
            float4 bv = *(const float4*)(&xs[pp][tx << 2]);
            acc[0][0] += av.x*bv.x; acc[0][1] += av.x*bv.y; acc[0][2] += av.x*bv.z; acc[0][3] += av.x*bv.w;
            acc[1][0] += av.y*bv.x; acc[1][1] += av.y*bv.y; acc[1][2] += av.y*bv.z; acc[1][3] += av.y*bv.w;
            acc[2][0] += av.z*bv.x; acc[2][1] += av.z*bv.y; acc[2][2] += av.z*bv.z; acc[2][3] += av.z*bv.w;
            acc[3][0] += av.w*bv.x; acc[3][1] += av.w*bv.y; acc[3][2] += av.w*bv.z; acc[3][3] += av.w*bv.w;
        }
        if (t < CH) {
            #pragma unroll 8
            for (int pp = 0; pp < 64; ++pp) sloc += xs[pp][t];
        }
    }

    float* pout = partials + (size_t)id * PSTRIDE;
    #pragma unroll
    for (int i = 0; i < 4; ++i) {
        float4 v = make_float4(acc[i][0], acc[i][1], acc[i][2], acc[i][3]);
        *(float4*)(pout + ((ty*4 + i) * 64 + tx*4)) = v;
    }
    if (t < CH) pout[4096 + t] = sloc;
}

// ---------------- K5: reduce partials, build cov, solve cov*w = p ----------------
__global__ void __launch_bounds__(256) k_solve(const float* __restrict__ partials,
        const int* __restrict__ counts, const float* __restrict__ pattern,
        float* __restrict__ params) {
    int bk = blockIdx.x;
    int t = threadIdx.x;
    __shared__ float M[64][66];      // augmented [cov | rhs@64]
    __shared__ float ssum[CH];
    __shared__ float wv[CH];
    __shared__ float red[2];

    const float* pp = partials + (size_t)bk * NCHUNK * PSTRIDE;
    for (int e = t; e < 4096; e += 256) {
        float v = 0.f;
        for (int ch = 0; ch < NCHUNK; ++ch) v += pp[(size_t)ch * PSTRIDE + e];
        M[e >> 6][e & 63] = v;       // sxx for now
    }
    if (t < CH) {
        float v = 0.f;
        for (int ch = 0; ch < NCHUNK; ++ch) v += pp[(size_t)ch * PSTRIDE + 4096 + t];
        ssum[t] = v;
    }
    __syncthreads();

    int cnt = counts[bk];
    float safe = fmaxf((float)cnt, 1.0f);
    float inv = 1.0f / safe;
    for (int e = t; e < 4096; e += 256) {
        int c = e >> 6, d = e & 63;
        float cov = M[c][d] * inv - (ssum[c] * inv) * (ssum[d] * inv);
        if (c == d) cov += EPSV;
        M[c][d] = cov;
    }
    if (t < CH) M[t][64] = pattern[t];
    __syncthreads();

    // forward elimination (SPD, no pivoting)
    int r = t >> 2, q = t & 3;
    for (int j = 0; j < 63; ++j) {
        if (r > j) {
            float f = M[r][j] / M[j][j];
            for (int d = j + 1 + q; d <= 64; d += 4) M[r][d] -= f * M[j][d];
        }
        __syncthreads();
    }
    // back substitution
    for (int j = 63; j >= 0; --j) {
        if (t == 0) wv[j] = M[j][64] / M[j][j];
        __syncthreads();
        if (t < j) M[t][64] -= M[t][j] * wv[j];
        __syncthreads();
    }

    if (t == 0) {
        float dp = 0.f, bias = 0.f;
        for (int c = 0; c < CH; ++c) {
            dp += pattern[c] * wv[c];
            bias += (ssum[c] * inv) * wv[c];
        }
        float denom = sqrtf(dp);
        float valid = (cnt >= MINSZ) ? 1.0f : 0.0f;
        float scale = (denom > 0.f) ? (valid / denom) : 0.0f;
        red[0] = scale;
        red[1] = bias * scale;
    }
    __syncthreads();
    if (t < CH) params[bk*66 + t] = wv[t] * red[0];
    if (t == 0) params[bk*66 + 64] = red[1];
    if (t == 1) params[bk*66 + 65] = 0.f;
}

// ---------------- K6: fused per-pixel score ----------------
__global__ void k_score(const float* __restrict__ x, const int* __restrict__ seg,
                        const float* __restrict__ params, float* __restrict__ out) {
    __shared__ float pw[NCLS][66];
    int t = threadIdx.x;
    int base = blockIdx.x * 256;
    int b = base / NPIX;
    for (int e = t; e < NCLS*66; e += 256)
        ((float*)pw)[e] = params[b*NCLS*66 + e];
    __syncthreads();

    int k = seg[base + t];
    int n = (base % NPIX) + t;
    const float* xb = x + (size_t)b * CH * NPIX + n;
    float a0 = 0.f, a1 = 0.f, a2 = 0.f, a3 = 0.f;
    #pragma unroll
    for (int c = 0; c < CH; c += 4) {
        a0 += xb[(size_t)(c+0) * NPIX] * pw[k][c+0];
        a1 += xb[(size_t)(c+1) * NPIX] * pw[k][c+1];
        a2 += xb[(size_t)(c+2) * NPIX] * pw[k][c+2];
        a3 += xb[(size_t)(c+3) * NPIX] * pw[k][c+3];
    }
    out[base + t] = (a0 + a1) + (a2 + a3) - pw[k][64];
}

// ---------------- launch ----------------
extern "C" void kernel_launch(void* const* d_in, const int* in_sizes, int n_in,
                              void* d_out, int out_size, void* d_ws, size_t ws_size,
                              hipStream_t stream) {
    const float* x       = (const float*)d_in[0];   // (B,C,H,W) fp32
    const float* pattern = (const float*)d_in[1];   // (C,) fp32
    const int*   seg     = (const int*)d_in[2];     // (B,H,W) int32
    float* out = (float*)d_out;

    float* wsf      = (float*)d_ws;
    float* gathered = wsf;                                             // B*N*CH
    float* partials = gathered + (size_t)BATCH * NPIX * CH;            // B*K*NCHUNK*PSTRIDE
    float* params   = partials + (size_t)BATCH * NCLS * NCHUNK * PSTRIDE; // B*K*66
    int* hist      = (int*)(params + BATCH * NCLS * 66);               // NBLK*NCLS
    int* blockbase = hist + NBLK * NCLS;                               // NBLK*NCLS
    int* counts    = blockbase + NBLK * NCLS;                          // B*K
    int* offsets   = counts + BATCH * NCLS;                            // B*K

    k_hist   <<<NBLK,               256, 0, stream>>>(seg, hist);
    k_counts <<<BATCH*NCLS,         256, 0, stream>>>(hist, counts);
    k_scan   <<<BATCH*NCLS,         256, 0, stream>>>(hist, counts, blockbase, offsets);
    k_scatter<<<NBLK,               256, 0, stream>>>(x, seg, blockbase, gathered);
    k_gemm   <<<BATCH*NCLS*NCHUNK,  256, 0, stream>>>(gathered, counts, offsets, partials);
    k_solve  <<<BATCH*NCLS,         256, 0, stream>>>(partials, counts, pattern, params);
    k_score  <<<NBLK,               256, 0, stream>>>(x, seg, params, out);
}

// Round 4
// 146.175 us; speedup vs baseline: 1.1952x; 1.1137x over previous
//
#include <hip/hip_runtime.h>
#include <math.h>

#define NCLS 20
#define CH 64
#define NPIX (384*384)
#define BATCH 2
#define MINSZ 5000
#define EPSV 1e-6f
#define NCHUNK 24
#define NBLK (BATCH*NPIX/256)      // 1152
#define BLKPERB (NPIX/256)         // 576
#define PSTRIDE 4160               // 4096 sxx + 64 sums

// ---------------- K1: per-block class histogram ----------------
__global__ void k_hist(const int* __restrict__ seg, int* __restrict__ hist) {
    __shared__ int h[NCLS];
    int t = threadIdx.x;
    if (t < NCLS) h[t] = 0;
    __syncthreads();
    int k = seg[blockIdx.x * 256 + t];
    atomicAdd(&h[k], 1);
    __syncthreads();
    if (t < NCLS) hist[blockIdx.x * NCLS + t] = h[t];
}

// ---------------- K2a: per-(b,k) counts ----------------
__global__ void k_counts(const int* __restrict__ hist, int* __restrict__ counts) {
    int bk = blockIdx.x;
    int b = bk / NCLS, k = bk % NCLS;
    __shared__ int sred[256];
    int t = threadIdx.x;
    int s = 0;
    for (int e = t; e < BLKPERB; e += 256) s += hist[(b*BLKPERB + e)*NCLS + k];
    sred[t] = s;
    __syncthreads();
    for (int st = 128; st > 0; st >>= 1) {
        if (t < st) sred[t] += sred[t + st];
        __syncthreads();
    }
    if (t == 0) counts[bk] = sred[0];
}

// ---------------- K2b: per-(b,k) exclusive scan over blocks ----------------
__global__ void k_scan(const int* __restrict__ hist, const int* __restrict__ counts,
                       int* __restrict__ blockbase, int* __restrict__ offsets) {
    int bk = blockIdx.x;
    int b = bk / NCLS;
    int k = bk % NCLS;
    __shared__ int sh[BLKPERB];
    int t = threadIdx.x;
    for (int e = t; e < BLKPERB; e += 256) sh[e] = hist[(b*BLKPERB + e)*NCLS + k];
    __syncthreads();
    if (t == 0) {
        int off = b * NPIX;
        for (int kk = b*NCLS; kk < bk; ++kk) off += counts[kk];
        offsets[bk] = off;
        int run = off;
        #pragma unroll 8
        for (int e = 0; e < BLKPERB; ++e) { int v = sh[e]; sh[e] = run; run += v; }
    }
    __syncthreads();
    for (int e = t; e < BLKPERB; e += 256) blockbase[(b*BLKPERB + e)*NCLS + k] = sh[e];
}

// ---------------- K3: LDS-staged class-sorted scatter (coalesced writes) ----------------
__global__ void __launch_bounds__(256) k_scatter(const float* __restrict__ x, const int* __restrict__ seg,
                          const int* __restrict__ blockbase, float* __restrict__ gathered) {
    __shared__ float tile[256 * 33];     // slot-major, stride 33 (pad) = 33 KB
    __shared__ int wcnt[4][NCLS];        // per-wave per-class counts
    __shared__ int sblk[NCLS];           // class start within block (sorted order)
    __shared__ int drow[256];            // dest row in `gathered` per sorted slot
    int t = threadIdx.x;
    int blk = blockIdx.x;
    int base = blk * 256;
    int b = base / NPIX;
    int n = (base % NPIX) + t;
    int k = seg[base + t];
    int wave = t >> 6, lane = t & 63;

    // deterministic stable rank via per-wave ballots
    int riw = 0;
    for (int cls = 0; cls < NCLS; ++cls) {
        unsigned long long m = __ballot(k == cls);
        if (lane == 0) wcnt[wave][cls] = __popcll(m);
        if (k == cls) riw = __popcll(m & ((1ull << lane) - 1ull));
    }
    __syncthreads();
    if (t < NCLS) {
        int s = 0;
        for (int c = 0; c < t; ++c) s += wcnt[0][c] + wcnt[1][c] + wcnt[2][c] + wcnt[3][c];
        sblk[t] = s;
    }
    __syncthreads();
    int rib = riw;
    for (int w = 0; w < 4; ++w) if (w < wave) rib += wcnt[w][k];
    int slot = sblk[k] + rib;            // sorted position within block (permutation of 0..255)
    drow[slot] = blockbase[blk * NCLS + k] + rib;
    const float* xb = x + (size_t)b * CH * NPIX + n;

    // two channel-phases of 32, so tile fits comfortably and all lanes stay active
    for (int ph = 0; ph < 2; ++ph) {
        __syncthreads();                 // protect tile + drow
        #pragma unroll 8
        for (int c = 0; c < 32; ++c)
            tile[slot * 33 + c] = xb[(size_t)(ph * 32 + c) * NPIX];
        __syncthreads();
        // copy out: rows in sorted order -> dest rows contiguous per class run
        #pragma unroll 8
        for (int it = 0; it < 32; ++it) {
            int f = it * 256 + t;
            int r = f >> 5, c = f & 31;
            gathered[(size_t)drow[r] * CH + ph * 32 + c] = tile[r * 33 + c];
        }
    }
}

// ---------------- K4: per-(b,k,chunk) rank-n update (sxx partials + sums) ----------------
__global__ void __launch_bounds__(256) k_gemm(const float* __restrict__ gathered,
        const int* __restrict__ counts, const int* __restrict__ offsets,
        float* __restrict__ partials) {
    __shared__ float xs[64][CH];     // 64 pixels x 64 channels, 16 KB
    int id = blockIdx.x;
    int chunk = id % NCHUNK;
    int bk = id / NCHUNK;
    int cnt = counts[bk];
    int off = offsets[bk];
    int csz = (cnt + NCHUNK - 1) / NCHUNK;
    int p0 = chunk * csz;
    int p1 = min(cnt, p0 + csz);
    int t = threadIdx.x;
    int tx = t & 15, ty = t >> 4;
    float acc[4][4] = {{0.f}};
    float sloc = 0.f;                // channel-sum for channel t (t<64)

    for (int p = p0; p < p1; p += 64) {
        __syncthreads();             // protect xs from previous tile's readers
        #pragma unroll
        for (int i = 0; i < 4; ++i) {
            int f = i * 256 + t;     // float4 id 0..1023
            int px = f >> 4;
            int c4 = (f & 15) << 2;
            float4 v = make_float4(0.f, 0.f, 0.f, 0.f);
            if (p + px < p1)
                v = *(const float4*)(gathered + (size_t)(off + p + px) * CH + c4);
            *(float4*)(&xs[px][c4]) = v;
        }
        __syncthreads();
        #pragma unroll 4
        for (int pp = 0; pp < 64; ++pp) {
            float4 av = *(const float4*)(&xs[pp][ty << 2]);
            float4 bv = *(const float4*)(&xs[pp][tx << 2]);
            acc[0][0] += av.x*bv.x; acc[0][1] += av.x*bv.y; acc[0][2] += av.x*bv.z; acc[0][3] += av.x*bv.w;
            acc[1][0] += av.y*bv.x; acc[1][1] += av.y*bv.y; acc[1][2] += av.y*bv.z; acc[1][3] += av.y*bv.w;
            acc[2][0] += av.z*bv.x; acc[2][1] += av.z*bv.y; acc[2][2] += av.z*bv.z; acc[2][3] += av.z*bv.w;
            acc[3][0] += av.w*bv.x; acc[3][1] += av.w*bv.y; acc[3][2] += av.w*bv.z; acc[3][3] += av.w*bv.w;
        }
        if (t < CH) {
            #pragma unroll 8
            for (int pp = 0; pp < 64; ++pp) sloc += xs[pp][t];
        }
    }

    float* pout = partials + (size_t)id * PSTRIDE;
    #pragma unroll
    for (int i = 0; i < 4; ++i) {
        float4 v = make_float4(acc[i][0], acc[i][1], acc[i][2], acc[i][3]);
        *(float4*)(pout + ((ty*4 + i) * 64 + tx*4)) = v;
    }
    if (t < CH) pout[4096 + t] = sloc;
}

// ---------------- K4b: parallel reduce of chunk partials ----------------
__global__ void __launch_bounds__(256) k_reduce(const float* __restrict__ partials,
        float* __restrict__ sxxred) {
    int id = blockIdx.x;             // bk*17 + slice
    int bk = id / 17, slice = id % 17;
    int t = threadIdx.x;
    const float* pp = partials + (size_t)bk * NCHUNK * PSTRIDE;
    if (slice < 16) {
        int e = slice * 256 + t;
        float v = 0.f;
        #pragma unroll
        for (int ch = 0; ch < NCHUNK; ++ch) v += pp[(size_t)ch * PSTRIDE + e];
        sxxred[(size_t)bk * PSTRIDE + e] = v;
    } else if (t < CH) {
        float v = 0.f;
        #pragma unroll
        for (int ch = 0; ch < NCHUNK; ++ch) v += pp[(size_t)ch * PSTRIDE + 4096 + t];
        sxxred[(size_t)bk * PSTRIDE + 4096 + t] = v;
    }
}

// ---------------- K5: build cov, Gauss-Jordan solve cov*w = p ----------------
__global__ void __launch_bounds__(256) k_solve(const float* __restrict__ sxxred,
        const int* __restrict__ counts, const float* __restrict__ pattern,
        float* __restrict__ params) {
    int bk = blockIdx.x;
    int t = threadIdx.x;
    __shared__ float M[64][67];      // augmented [cov | rhs@64], stride 67 (odd) for banks
    __shared__ float ssum[CH];
    __shared__ float wv[CH];
    __shared__ float red[2];

    const float* pp = sxxred + (size_t)bk * PSTRIDE;
    int cnt = counts[bk];
    float inv = 1.0f / fmaxf((float)cnt, 1.0f);
    if (t < CH) ssum[t] = pp[4096 + t];
    __syncthreads();
    for (int e = t; e < 4096; e += 256) {
        int c = e >> 6, d = e & 63;
        float cov = pp[e] * inv - (ssum[c] * inv) * (ssum[d] * inv);
        if (c == d) cov += EPSV;
        M[c][d] = cov;
    }
    if (t < CH) M[t][64] = pattern[t];
    __syncthreads();

    // Gauss-Jordan: eliminate col j from ALL rows r != j. One barrier per step.
    // Reads: row j (never written this step), col j (never written this step).
    int r = t >> 2, q = t & 3;
    for (int j = 0; j < 64; ++j) {
        float f = M[r][j] / M[j][j];
        if (r != j) {
            #pragma unroll 4
            for (int d = j + 1 + q; d <= 64; d += 4)
                M[r][d] -= f * M[j][d];
        }
        __syncthreads();
    }
    if (t < CH) wv[t] = M[t][64] / M[t][t];
    __syncthreads();

    // epilogue: wave-0 shuffle reductions (t 0..63 = one wave)
    if (t < CH) {
        float w = wv[t];
        float dp = pattern[t] * w;
        float bias = (ssum[t] * inv) * w;
        #pragma unroll
        for (int o = 32; o > 0; o >>= 1) {
            dp += __shfl_xor(dp, o);
            bias += __shfl_xor(bias, o);
        }
        if (t == 0) {
            float denom = sqrtf(dp);
            float valid = (cnt >= MINSZ) ? 1.0f : 0.0f;
            float scale = (denom > 0.f) ? (valid / denom) : 0.0f;
            red[0] = scale;
            red[1] = bias * scale;
        }
    }
    __syncthreads();
    if (t < CH) params[bk*66 + t] = wv[t] * red[0];
    if (t == 0) params[bk*66 + 64] = red[1];
    if (t == 1) params[bk*66 + 65] = 0.f;
}

// ---------------- K6: fused per-pixel score ----------------
__global__ void k_score(const float* __restrict__ x, const int* __restrict__ seg,
                        const float* __restrict__ params, float* __restrict__ out) {
    __shared__ float pw[NCLS][66];
    int t = threadIdx.x;
    int base = blockIdx.x * 256;
    int b = base / NPIX;
    for (int e = t; e < NCLS*66; e += 256)
        ((float*)pw)[e] = params[b*NCLS*66 + e];
    __syncthreads();

    int k = seg[base + t];
    int n = (base % NPIX) + t;
    const float* xb = x + (size_t)b * CH * NPIX + n;
    float a0 = 0.f, a1 = 0.f, a2 = 0.f, a3 = 0.f;
    #pragma unroll
    for (int c = 0; c < CH; c += 4) {
        a0 += xb[(size_t)(c+0) * NPIX] * pw[k][c+0];
        a1 += xb[(size_t)(c+1) * NPIX] * pw[k][c+1];
        a2 += xb[(size_t)(c+2) * NPIX] * pw[k][c+2];
        a3 += xb[(size_t)(c+3) * NPIX] * pw[k][c+3];
    }
    out[base + t] = (a0 + a1) + (a2 + a3) - pw[k][64];
}

// ---------------- launch ----------------
extern "C" void kernel_launch(void* const* d_in, const int* in_sizes, int n_in,
                              void* d_out, int out_size, void* d_ws, size_t ws_size,
                              hipStream_t stream) {
    const float* x       = (const float*)d_in[0];   // (B,C,H,W) fp32
    const float* pattern = (const float*)d_in[1];   // (C,) fp32
    const int*   seg     = (const int*)d_in[2];     // (B,H,W) int32
    float* out = (float*)d_out;

    float* wsf      = (float*)d_ws;
    float* gathered = wsf;                                             // B*N*CH
    float* partials = gathered + (size_t)BATCH * NPIX * CH;            // B*K*NCHUNK*PSTRIDE
    float* sxxred   = partials + (size_t)BATCH * NCLS * NCHUNK * PSTRIDE; // B*K*PSTRIDE
    float* params   = sxxred + (size_t)BATCH * NCLS * PSTRIDE;         // B*K*66
    int* hist      = (int*)(params + BATCH * NCLS * 66);               // NBLK*NCLS
    int* blockbase = hist + NBLK * NCLS;                               // NBLK*NCLS
    int* counts    = blockbase + NBLK * NCLS;                          // B*K
    int* offsets   = counts + BATCH * NCLS;                            // B*K

    k_hist   <<<NBLK,                256, 0, stream>>>(seg, hist);
    k_counts <<<BATCH*NCLS,          256, 0, stream>>>(hist, counts);
    k_scan   <<<BATCH*NCLS,          256, 0, stream>>>(hist, counts, blockbase, offsets);
    k_scatter<<<NBLK,                256, 0, stream>>>(x, seg, blockbase, gathered);
    k_gemm   <<<BATCH*NCLS*NCHUNK,   256, 0, stream>>>(gathered, counts, offsets, partials);
    k_reduce <<<BATCH*NCLS*17,       256, 0, stream>>>(partials, sxxred);
    k_solve  <<<BATCH*NCLS,          256, 0, stream>>>(sxxred, counts, pattern, params);
    k_score  <<<NBLK,                256, 0, stream>>>(x, seg, params, out);
}

// Round 6
// 117.542 us; speedup vs baseline: 1.4864x; 1.2436x over previous
//
#include <hip/hip_runtime.h>
#include <math.h>

#define NCLS 20
#define CH 64
#define NPIX (384*384)
#define BATCH 2
#define MINSZ 5000
#define EPSV 1e-6f
#define NCHUNK 32
#define NBLK (BATCH*NPIX/256)      // 1152
#define BLKPERB (NPIX/576)         // unused name guard
#undef BLKPERB
#define BLKPERB (NPIX/256)         // 576
#define PSTRIDE 4160               // 4096 sxx + 64 sums
#define XSTR 72                    // channel-major LDS stride (144B, 16B-aligned rows)

typedef __attribute__((ext_vector_type(8))) __bf16 bf16x8;
typedef __attribute__((ext_vector_type(4))) float  f32x4;

static __device__ inline unsigned short f2bf(float f) {
    unsigned u = __builtin_bit_cast(unsigned, f);
    return (unsigned short)((u + 0x7fffu + ((u >> 16) & 1u)) >> 16);
}
static __device__ inline float bf2f(unsigned us) {
    unsigned u = us << 16;
    return __builtin_bit_cast(float, u);
}

// ---------------- K1: per-block class histogram ----------------
__global__ void k_hist(const int* __restrict__ seg, int* __restrict__ hist) {
    __shared__ int h[NCLS];
    int t = threadIdx.x;
    if (t < NCLS) h[t] = 0;
    __syncthreads();
    int k = seg[blockIdx.x * 256 + t];
    atomicAdd(&h[k], 1);
    __syncthreads();
    if (t < NCLS) hist[blockIdx.x * NCLS + t] = h[t];
}

// ---------------- K2a: per-(b,k) counts ----------------
__global__ void k_counts(const int* __restrict__ hist, int* __restrict__ counts) {
    int bk = blockIdx.x;
    int b = bk / NCLS, k = bk % NCLS;
    __shared__ int sred[256];
    int t = threadIdx.x;
    int s = 0;
    for (int e = t; e < BLKPERB; e += 256) s += hist[(b*BLKPERB + e)*NCLS + k];
    sred[t] = s;
    __syncthreads();
    for (int st = 128; st > 0; st >>= 1) {
        if (t < st) sred[t] += sred[t + st];
        __syncthreads();
    }
    if (t == 0) counts[bk] = sred[0];
}

// ---------------- K2b: per-(b,k) exclusive scan over blocks ----------------
__global__ void k_scan(const int* __restrict__ hist, const int* __restrict__ counts,
                       int* __restrict__ blockbase, int* __restrict__ offsets) {
    int bk = blockIdx.x;
    int b = bk / NCLS;
    int k = bk % NCLS;
    __shared__ int sh[BLKPERB];
    int t = threadIdx.x;
    for (int e = t; e < BLKPERB; e += 256) sh[e] = hist[(b*BLKPERB + e)*NCLS + k];
    __syncthreads();
    if (t == 0) {
        int off = b * NPIX;
        for (int kk = b*NCLS; kk < bk; ++kk) off += counts[kk];
        offsets[bk] = off;
        int run = off;
        #pragma unroll 8
        for (int e = 0; e < BLKPERB; ++e) { int v = sh[e]; sh[e] = run; run += v; }
    }
    __syncthreads();
    for (int e = t; e < BLKPERB; e += 256) blockbase[(b*BLKPERB + e)*NCLS + k] = sh[e];
}

// ---------------- K3: LDS-staged class-sorted scatter -> bf16 gathered ----------------
__global__ void __launch_bounds__(256) k_scatter(const float* __restrict__ x, const int* __restrict__ seg,
                          const int* __restrict__ blockbase, unsigned short* __restrict__ gathered) {
    __shared__ float tile[256 * 33];     // slot-major, stride 33 (pad) = 33 KB
    __shared__ int wcnt[4][NCLS];
    __shared__ int sblk[NCLS];
    __shared__ int drow[256];
    int t = threadIdx.x;
    int blk = blockIdx.x;
    int base = blk * 256;
    int b = base / NPIX;
    int n = (base % NPIX) + t;
    int k = seg[base + t];
    int wave = t >> 6, lane = t & 63;

    int riw = 0;
    for (int cls = 0; cls < NCLS; ++cls) {
        unsigned long long m = __ballot(k == cls);
        if (lane == 0) wcnt[wave][cls] = __popcll(m);
        if (k == cls) riw = __popcll(m & ((1ull << lane) - 1ull));
    }
    __syncthreads();
    if (t < NCLS) {
        int s = 0;
        for (int c = 0; c < t; ++c) s += wcnt[0][c] + wcnt[1][c] + wcnt[2][c] + wcnt[3][c];
        sblk[t] = s;
    }
    __syncthreads();
    int rib = riw;
    for (int w = 0; w < 4; ++w) if (w < wave) rib += wcnt[w][k];
    int slot = sblk[k] + rib;
    drow[slot] = blockbase[blk * NCLS + k] + rib;
    const float* xb = x + (size_t)b * CH * NPIX + n;

    for (int ph = 0; ph < 2; ++ph) {
        __syncthreads();
        #pragma unroll 8
        for (int c = 0; c < 32; ++c)
            tile[slot * 33 + c] = xb[(size_t)(ph * 32 + c) * NPIX];
        __syncthreads();
        // copy out as packed bf16 pairs: rows sorted -> dest rows contiguous per class run
        #pragma unroll 8
        for (int it = 0; it < 16; ++it) {
            int f = it * 256 + t;
            int r = f >> 4, c2 = f & 15;
            float a = tile[r * 33 + c2 * 2];
            float bq = tile[r * 33 + c2 * 2 + 1];
            unsigned pk = (unsigned)f2bf(a) | ((unsigned)f2bf(bq) << 16);
            *(unsigned*)(gathered + (size_t)drow[r] * CH + ph * 32 + c2 * 2) = pk;
        }
    }
}

// ---------------- K4: per-(b,k,chunk) sxx via bf16 MFMA (no inline asm) ----------------
__global__ void __launch_bounds__(256) k_gemm(const unsigned short* __restrict__ gathered,
        const int* __restrict__ counts, const int* __restrict__ offsets,
        float* __restrict__ partials) {
    // channel-major transposed tile: element (p,c) at xt[c*XSTR + p]
    __shared__ __align__(16) unsigned short xt[CH * XSTR];   // 9.2 KB
    __shared__ float wsum[4][CH];
    int id = blockIdx.x;
    int chunk = id % NCHUNK;
    int bk = id / NCHUNK;
    int cnt = counts[bk];
    int off = offsets[bk];
    int csz = (cnt + NCHUNK - 1) / NCHUNK;
    int p0 = chunk * csz;
    int p1 = min(cnt, p0 + csz);
    int t = threadIdx.x;
    int w = t >> 6, l = t & 63, g = l >> 4, c15 = l & 15;
    int cg = t & 7;                       // this thread's fixed 8-channel group

    f32x4 acc[4];
    #pragma unroll
    for (int nb = 0; nb < 4; ++nb) { f32x4 z = {0.f,0.f,0.f,0.f}; acc[nb] = z; }
    float ssum[8] = {0.f,0.f,0.f,0.f,0.f,0.f,0.f,0.f};

    for (int tp = p0; tp < p1; tp += 64) {
        __syncthreads();                 // protect xt from previous iter's readers
        #pragma unroll
        for (int it = 0; it < 2; ++it) {
            int p = it * 32 + (t >> 3);  // pixel within tile, 0..63
            int gp = tp + p;
            uint4 v = make_uint4(0u, 0u, 0u, 0u);
            if (gp < p1)
                v = *(const uint4*)(gathered + (size_t)(off + gp) * CH + cg * 8);
            unsigned arr[4] = {v.x, v.y, v.z, v.w};
            #pragma unroll
            for (int q = 0; q < 4; ++q) {
                unsigned lo = arr[q] & 0xffffu, hi = arr[q] >> 16;
                xt[(8*cg + 2*q    ) * XSTR + p] = (unsigned short)lo;
                xt[(8*cg + 2*q + 1) * XSTR + p] = (unsigned short)hi;
                if (gp < p1) {
                    ssum[2*q]   += bf2f(lo);
                    ssum[2*q+1] += bf2f(hi);
                }
            }
        }
        __syncthreads();
        #pragma unroll
        for (int kc = 0; kc < 2; ++kc) {
            // lane l reads 8 consecutive pixels (k-slots) at its channel row;
            // identical construction for A and B -> any ISA k-permutation cancels.
            bf16x8 fr0 = *(const bf16x8*)(xt + ( 0 + c15) * XSTR + kc * 32 + 8 * g);
            bf16x8 fr1 = *(const bf16x8*)(xt + (16 + c15) * XSTR + kc * 32 + 8 * g);
            bf16x8 fr2 = *(const bf16x8*)(xt + (32 + c15) * XSTR + kc * 32 + 8 * g);
            bf16x8 fr3 = *(const bf16x8*)(xt + (48 + c15) * XSTR + kc * 32 + 8 * g);
            bf16x8 fa;
            if      (w == 0) fa = fr0;
            else if (w == 1) fa = fr1;
            else if (w == 2) fa = fr2;
            else             fa = fr3;
            acc[0] = __builtin_amdgcn_mfma_f32_16x16x32_bf16(fa, fr0, acc[0], 0, 0, 0);
            acc[1] = __builtin_amdgcn_mfma_f32_16x16x32_bf16(fa, fr1, acc[1], 0, 0, 0);
            acc[2] = __builtin_amdgcn_mfma_f32_16x16x32_bf16(fa, fr2, acc[2], 0, 0, 0);
            acc[3] = __builtin_amdgcn_mfma_f32_16x16x32_bf16(fa, fr3, acc[3], 0, 0, 0);
        }
    }

    // write sxx partial: wave w owns rows 16w..16w+15; C/D: col=l&15, row=4*(l>>4)+reg
    float* pout = partials + (size_t)id * PSTRIDE;
    #pragma unroll
    for (int nb = 0; nb < 4; ++nb)
        #pragma unroll
        for (int r = 0; r < 4; ++r)
            pout[(16*w + 4*g + r) * 64 + 16*nb + c15] = acc[nb][r];

    // deterministic channel-sum reduce: lanes sharing (l&7) hold same channel group
    #pragma unroll
    for (int o = 8; o < 64; o <<= 1)
        #pragma unroll
        for (int j = 0; j < 8; ++j) ssum[j] += __shfl_xor(ssum[j], o);
    if (l < 8) {
        #pragma unroll
        for (int j = 0; j < 8; ++j) wsum[w][l * 8 + j] = ssum[j];
    }
    __syncthreads();
    if (t < CH) pout[4096 + t] = wsum[0][t] + wsum[1][t] + wsum[2][t] + wsum[3][t];
}

// ---------------- K4b: parallel reduce of chunk partials ----------------
__global__ void __launch_bounds__(256) k_reduce(const float* __restrict__ partials,
        float* __restrict__ sxxred) {
    int id = blockIdx.x;             // bk*17 + slice
    int bk = id / 17, slice = id % 17;
    int t = threadIdx.x;
    const float* pp = partials + (size_t)bk * NCHUNK * PSTRIDE;
    if (slice < 16) {
        int e = slice * 256 + t;
        float v = 0.f;
        #pragma unroll 8
        for (int ch = 0; ch < NCHUNK; ++ch) v += pp[(size_t)ch * PSTRIDE + e];
        sxxred[(size_t)bk * PSTRIDE + e] = v;
    } else if (t < CH) {
        float v = 0.f;
        #pragma unroll 8
        for (int ch = 0; ch < NCHUNK; ++ch) v += pp[(size_t)ch * PSTRIDE + 4096 + t];
        sxxred[(size_t)bk * PSTRIDE + 4096 + t] = v;
    }
}

// ---------------- K5: build cov, Gauss-Jordan solve cov*w = p ----------------
__global__ void __launch_bounds__(256) k_solve(const float* __restrict__ sxxred,
        const int* __restrict__ counts, const float* __restrict__ pattern,
        float* __restrict__ params) {
    int bk = blockIdx.x;
    int t = threadIdx.x;
    __shared__ float M[64][67];
    __shared__ float ssum[CH];
    __shared__ float wv[CH];
    __shared__ float red[2];

    const float* pp = sxxred + (size_t)bk * PSTRIDE;
    int cnt = counts[bk];
    float inv = 1.0f / fmaxf((float)cnt, 1.0f);
    if (t < CH) ssum[t] = pp[4096 + t];
    __syncthreads();
    for (int e = t; e < 4096; e += 256) {
        int c = e >> 6, d = e & 63;
        float cov = pp[e] * inv - (ssum[c] * inv) * (ssum[d] * inv);
        if (c == d) cov += EPSV;
        M[c][d] = cov;
    }
    if (t < CH) M[t][64] = pattern[t];
    __syncthreads();

    int r = t >> 2, q = t & 3;
    for (int j = 0; j < 64; ++j) {
        float f = M[r][j] / M[j][j];
        if (r != j) {
            #pragma unroll 4
            for (int d = j + 1 + q; d <= 64; d += 4)
                M[r][d] -= f * M[j][d];
        }
        __syncthreads();
    }
    if (t < CH) wv[t] = M[t][64] / M[t][t];
    __syncthreads();

    if (t < CH) {
        float wvt = wv[t];
        float dp = pattern[t] * wvt;
        float bias = (ssum[t] * inv) * wvt;
        #pragma unroll
        for (int o = 32; o > 0; o >>= 1) {
            dp += __shfl_xor(dp, o);
            bias += __shfl_xor(bias, o);
        }
        if (t == 0) {
            float denom = sqrtf(dp);
            float valid = (cnt >= MINSZ) ? 1.0f : 0.0f;
            float scale = (denom > 0.f) ? (valid / denom) : 0.0f;
            red[0] = scale;
            red[1] = bias * scale;
        }
    }
    __syncthreads();
    if (t < CH) params[bk*66 + t] = wv[t] * red[0];
    if (t == 0) params[bk*66 + 64] = red[1];
    if (t == 1) params[bk*66 + 65] = 0.f;
}

// ---------------- K6: fused per-pixel score ----------------
__global__ void k_score(const float* __restrict__ x, const int* __restrict__ seg,
                        const float* __restrict__ params, float* __restrict__ out) {
    __shared__ float pw[NCLS][66];
    int t = threadIdx.x;
    int base = blockIdx.x * 256;
    int b = base / NPIX;
    for (int e = t; e < NCLS*66; e += 256)
        ((float*)pw)[e] = params[b*NCLS*66 + e];
    __syncthreads();

    int k = seg[base + t];
    int n = (base % NPIX) + t;
    const float* xb = x + (size_t)b * CH * NPIX + n;
    float a0 = 0.f, a1 = 0.f, a2 = 0.f, a3 = 0.f;
    #pragma unroll
    for (int c = 0; c < CH; c += 4) {
        a0 += xb[(size_t)(c+0) * NPIX] * pw[k][c+0];
        a1 += xb[(size_t)(c+1) * NPIX] * pw[k][c+1];
        a2 += xb[(size_t)(c+2) * NPIX] * pw[k][c+2];
        a3 += xb[(size_t)(c+3) * NPIX] * pw[k][c+3];
    }
    out[base + t] = (a0 + a1) + (a2 + a3) - pw[k][64];
}

// ---------------- launch ----------------
extern "C" void kernel_launch(void* const* d_in, const int* in_sizes, int n_in,
                              void* d_out, int out_size, void* d_ws, size_t ws_size,
                              hipStream_t stream) {
    const float* x       = (const float*)d_in[0];   // (B,C,H,W) fp32
    const float* pattern = (const float*)d_in[1];   // (C,) fp32
    const int*   seg     = (const int*)d_in[2];     // (B,H,W) int32
    float* out = (float*)d_out;

    unsigned short* gathered = (unsigned short*)d_ws;                  // B*N*CH bf16
    float* partials = (float*)(gathered + (size_t)BATCH * NPIX * CH);  // B*K*NCHUNK*PSTRIDE
    float* sxxred   = partials + (size_t)BATCH * NCLS * NCHUNK * PSTRIDE; // B*K*PSTRIDE
    float* params   = sxxred + (size_t)BATCH * NCLS * PSTRIDE;         // B*K*66
    int* hist      = (int*)(params + BATCH * NCLS * 66);               // NBLK*NCLS
    int* blockbase = hist + NBLK * NCLS;                               // NBLK*NCLS
    int* counts    = blockbase + NBLK * NCLS;                          // B*K
    int* offsets   = counts + BATCH * NCLS;                            // B*K

    k_hist   <<<NBLK,                256, 0, stream>>>(seg, hist);
    k_counts <<<BATCH*NCLS,          256, 0, stream>>>(hist, counts);
    k_scan   <<<BATCH*NCLS,          256, 0, stream>>>(hist, counts, blockbase, offsets);
    k_scatter<<<NBLK,                256, 0, stream>>>(x, seg, blockbase, gathered);
    k_gemm   <<<BATCH*NCLS*NCHUNK,   256, 0, stream>>>(gathered, counts, offsets, partials);
    k_reduce <<<BATCH*NCLS*17,       256, 0, stream>>>(partials, sxxred);
    k_solve  <<<BATCH*NCLS,          256, 0, stream>>>(sxxred, counts, pattern, params);
    k_score  <<<NBLK,                256, 0, stream>>>(x, seg, params, out);
}

// Round 7
// 105.835 us; speedup vs baseline: 1.6508x; 1.1106x over previous
//
#include <hip/hip_runtime.h>
#include <math.h>

#define NCLS 20
#define CH 64
#define NPIX (384*384)
#define BATCH 2
#define MINSZ 5000
#define EPSV 1e-6f
#define NCHUNK 16
#define NBLK (BATCH*NPIX/256)      // 1152
#define BLKPERB (NPIX/256)         // 576
#define PSTRIDE 4160               // 4096 sxx + 64 sums
#define XSTR 72                    // base channel-major stride (elems)
#define ROWOFF(c) ((c)*XSTR + ((c)>>3)*8)   // +8 elems pad every 8 rows: spreads banks

typedef __attribute__((ext_vector_type(8))) __bf16 bf16x8;
typedef __attribute__((ext_vector_type(4))) float  f32x4;

static __device__ inline unsigned short f2bf(float f) {
    unsigned u = __builtin_bit_cast(unsigned, f);
    return (unsigned short)((u + 0x7fffu + ((u >> 16) & 1u)) >> 16);
}
static __device__ inline float bf2f(unsigned us) {
    unsigned u = us << 16;
    return __builtin_bit_cast(float, u);
}

// ---------------- K1: per-block class histogram ----------------
__global__ void k_hist(const int* __restrict__ seg, int* __restrict__ hist) {
    __shared__ int h[NCLS];
    int t = threadIdx.x;
    if (t < NCLS) h[t] = 0;
    __syncthreads();
    int k = seg[blockIdx.x * 256 + t];
    atomicAdd(&h[k], 1);
    __syncthreads();
    if (t < NCLS) hist[blockIdx.x * NCLS + t] = h[t];
}

// ---------------- K2: fused counts + parallel scan ----------------
// One block per (b,k): per-class totals (for offsets+counts) and a parallel
// exclusive scan over the 576 per-block histogram entries of class k.
__global__ void __launch_bounds__(256) k_scanall(const int* __restrict__ hist,
        int* __restrict__ counts, int* __restrict__ blockbase, int* __restrict__ offsets) {
    int bk = blockIdx.x;
    int b = bk / NCLS, k = bk % NCLS;
    int t = threadIdx.x;
    __shared__ int sh[BLKPERB];
    __shared__ int part[NCLS][12];
    __shared__ int ctot[NCLS];
    __shared__ int tpA[256], tpB[256];
    __shared__ int soff;

    const int* hb = hist + (size_t)b * BLKPERB * NCLS;
    for (int e = t; e < BLKPERB; e += 256) sh[e] = hb[e * NCLS + k];
    if (t < NCLS * 12) {
        int kk = t / 12, sub = t % 12;
        int s = 0;
        #pragma unroll 8
        for (int e = sub * 48; e < sub * 48 + 48; ++e) s += hb[e * NCLS + kk];
        part[kk][sub] = s;
    }
    __syncthreads();
    if (t < NCLS) {
        int s = 0;
        #pragma unroll
        for (int j = 0; j < 12; ++j) s += part[t][j];
        ctot[t] = s;
    }
    __syncthreads();
    if (t == 0) {
        int off = b * NPIX;
        for (int kk = 0; kk < k; ++kk) off += ctot[kk];
        soff = off;
        offsets[bk] = off;
        counts[bk] = ctot[k];
    }
    // local inclusive over 3 owned elems (576 = 192*3)
    int s0 = 0, s1 = 0, s2 = 0;
    if (t < 192) {
        s0 = sh[3*t];
        s1 = s0 + sh[3*t + 1];
        s2 = s1 + sh[3*t + 2];
    }
    int mytot = (t < 192) ? s2 : 0;
    tpA[t] = mytot;
    __syncthreads();
    // Hillis-Steele inclusive scan, 8 ping-pong steps
    tpB[t] = tpA[t] + ((t >= 1)   ? tpA[t-1]   : 0); __syncthreads();
    tpA[t] = tpB[t] + ((t >= 2)   ? tpB[t-2]   : 0); __syncthreads();
    tpB[t] = tpA[t] + ((t >= 4)   ? tpA[t-4]   : 0); __syncthreads();
    tpA[t] = tpB[t] + ((t >= 8)   ? tpB[t-8]   : 0); __syncthreads();
    tpB[t] = tpA[t] + ((t >= 16)  ? tpA[t-16]  : 0); __syncthreads();
    tpA[t] = tpB[t] + ((t >= 32)  ? tpB[t-32]  : 0); __syncthreads();
    tpB[t] = tpA[t] + ((t >= 64)  ? tpA[t-64]  : 0); __syncthreads();
    tpA[t] = tpB[t] + ((t >= 128) ? tpB[t-128] : 0); __syncthreads();
    if (t < 192) {
        int excl = soff + tpA[t] - mytot;     // exclusive prefix + global offset
        int* bb = blockbase + ((size_t)b * BLKPERB) * NCLS + k;
        bb[(3*t    ) * NCLS] = excl;
        bb[(3*t + 1) * NCLS] = excl + s0;
        bb[(3*t + 2) * NCLS] = excl + s1;
    }
}

// ---------------- K3: LDS-staged class-sorted scatter -> bf16 gathered ----------------
__global__ void __launch_bounds__(256) k_scatter(const float* __restrict__ x, const int* __restrict__ seg,
                          const int* __restrict__ blockbase, unsigned short* __restrict__ gathered) {
    __shared__ float tile[256 * 33];     // slot-major, stride 33 (pad) = 33 KB
    __shared__ int wcnt[4][NCLS];
    __shared__ int sblk[NCLS];
    __shared__ int drow[256];
    int t = threadIdx.x;
    int blk = blockIdx.x;
    int base = blk * 256;
    int b = base / NPIX;
    int n = (base % NPIX) + t;
    int k = seg[base + t];
    int wave = t >> 6, lane = t & 63;

    int riw = 0;
    for (int cls = 0; cls < NCLS; ++cls) {
        unsigned long long m = __ballot(k == cls);
        if (lane == 0) wcnt[wave][cls] = __popcll(m);
        if (k == cls) riw = __popcll(m & ((1ull << lane) - 1ull));
    }
    __syncthreads();
    if (t < NCLS) {
        int s = 0;
        for (int c = 0; c < t; ++c) s += wcnt[0][c] + wcnt[1][c] + wcnt[2][c] + wcnt[3][c];
        sblk[t] = s;
    }
    __syncthreads();
    int rib = riw;
    for (int w = 0; w < 4; ++w) if (w < wave) rib += wcnt[w][k];
    int slot = sblk[k] + rib;
    drow[slot] = blockbase[blk * NCLS + k] + rib;
    const float* xb = x + (size_t)b * CH * NPIX + n;

    for (int ph = 0; ph < 2; ++ph) {
        __syncthreads();
        #pragma unroll 8
        for (int c = 0; c < 32; ++c)
            tile[slot * 33 + c] = xb[(size_t)(ph * 32 + c) * NPIX];
        __syncthreads();
        #pragma unroll 8
        for (int it = 0; it < 16; ++it) {
            int f = it * 256 + t;
            int r = f >> 4, c2 = f & 15;
            float a = tile[r * 33 + c2 * 2];
            float bq = tile[r * 33 + c2 * 2 + 1];
            unsigned pk = (unsigned)f2bf(a) | ((unsigned)f2bf(bq) << 16);
            *(unsigned*)(gathered + (size_t)drow[r] * CH + ph * 32 + c2 * 2) = pk;
        }
    }
}

// ---------------- K4: per-(b,k,chunk) sxx via bf16 MFMA ----------------
__global__ void __launch_bounds__(256) k_gemm(const unsigned short* __restrict__ gathered,
        const int* __restrict__ counts, const int* __restrict__ offsets,
        float* __restrict__ partials) {
    // channel-major transposed tile: element (p,c) at xt[ROWOFF(c) + p]
    __shared__ __align__(16) unsigned short xt[64 * XSTR + 7 * 8];   // ~9.3 KB
    __shared__ float wsum[4][CH];
    int id = blockIdx.x;
    int chunk = id % NCHUNK;
    int bk = id / NCHUNK;
    int cnt = counts[bk];
    int off = offsets[bk];
    int csz = (cnt + NCHUNK - 1) / NCHUNK;
    int p0 = chunk * csz;
    int pend = min(cnt, p0 + csz);
    int t = threadIdx.x;
    int w = t >> 6, l = t & 63, g = l >> 4, c15 = l & 15;
    int cg = t & 7;                       // channel group (8 channels)
    int ppair = t >> 3;                   // pixel pair 0..31

    f32x4 acc[4];
    #pragma unroll
    for (int nb = 0; nb < 4; ++nb) { f32x4 z = {0.f,0.f,0.f,0.f}; acc[nb] = z; }
    float ssum[8] = {0.f,0.f,0.f,0.f,0.f,0.f,0.f,0.f};

    for (int tp = p0; tp < pend; tp += 64) {
        __syncthreads();                 // protect xt from previous iter's readers
        // stage 64 pixels x 64 channels, packed pixel-pairs -> b32 writes (~2-way banks)
        {
            int gp0 = tp + 2 * ppair, gp1 = gp0 + 1;
            uint4 v0 = make_uint4(0u,0u,0u,0u), v1 = make_uint4(0u,0u,0u,0u);
            if (gp0 < pend) v0 = *(const uint4*)(gathered + (size_t)(off + gp0) * CH + cg * 8);
            if (gp1 < pend) v1 = *(const uint4*)(gathered + (size_t)(off + gp1) * CH + cg * 8);
            unsigned a0[4] = {v0.x, v0.y, v0.z, v0.w};
            unsigned a1[4] = {v1.x, v1.y, v1.z, v1.w};
            #pragma unroll
            for (int q = 0; q < 4; ++q) {
                unsigned lo0 = a0[q] & 0xffffu, hi0 = a0[q] >> 16;
                unsigned lo1 = a1[q] & 0xffffu, hi1 = a1[q] >> 16;
                ssum[2*q]   += bf2f(lo0) + bf2f(lo1);   // zeros when out of range
                ssum[2*q+1] += bf2f(hi0) + bf2f(hi1);
                int ch0 = 8 * cg + 2 * q;
                *(unsigned*)(xt + ROWOFF(ch0)     + 2 * ppair) = lo0 | (lo1 << 16);
                *(unsigned*)(xt + ROWOFF(ch0 + 1) + 2 * ppair) = hi0 | (hi1 << 16);
            }
        }
        __syncthreads();
        #pragma unroll
        for (int kc = 0; kc < 2; ++kc) {
            // lane reads 8 consecutive pixels (k-slots) of its channel row;
            // identical construction for A and B -> any ISA k-permutation cancels.
            bf16x8 fr0 = *(const bf16x8*)(xt + ROWOFF( 0 + c15) + kc * 32 + 8 * g);
            bf16x8 fr1 = *(const bf16x8*)(xt + ROWOFF(16 + c15) + kc * 32 + 8 * g);
            bf16x8 fr2 = *(const bf16x8*)(xt + ROWOFF(32 + c15) + kc * 32 + 8 * g);
            bf16x8 fr3 = *(const bf16x8*)(xt + ROWOFF(48 + c15) + kc * 32 + 8 * g);
            bf16x8 fa;
            if      (w == 0) fa = fr0;
            else if (w == 1) fa = fr1;
            else if (w == 2) fa = fr2;
            else             fa = fr3;
            acc[0] = __builtin_amdgcn_mfma_f32_16x16x32_bf16(fa, fr0, acc[0], 0, 0, 0);
            acc[1] = __builtin_amdgcn_mfma_f32_16x16x32_bf16(fa, fr1, acc[1], 0, 0, 0);
            acc[2] = __builtin_amdgcn_mfma_f32_16x16x32_bf16(fa, fr2, acc[2], 0, 0, 0);
            acc[3] = __builtin_amdgcn_mfma_f32_16x16x32_bf16(fa, fr3, acc[3], 0, 0, 0);
        }
    }

    // write sxx partial: wave w owns rows 16w..16w+15; C/D: col=l&15, row=4*(l>>4)+reg
    float* pout = partials + (size_t)id * PSTRIDE;
    #pragma unroll
    for (int nb = 0; nb < 4; ++nb)
        #pragma unroll
        for (int r = 0; r < 4; ++r)
            pout[(16*w + 4*g + r) * 64 + 16*nb + c15] = acc[nb][r];

    // deterministic channel-sum reduce: lanes sharing (l&7) hold same channel group
    #pragma unroll
    for (int o = 8; o < 64; o <<= 1)
        #pragma unroll
        for (int j = 0; j < 8; ++j) ssum[j] += __shfl_xor(ssum[j], o);
    if (l < 8) {
        #pragma unroll
        for (int j = 0; j < 8; ++j) wsum[w][l * 8 + j] = ssum[j];
    }
    __syncthreads();
    if (t < CH) pout[4096 + t] = wsum[0][t] + wsum[1][t] + wsum[2][t] + wsum[3][t];
}

// ---------------- K5: fused chunk-reduce + cov + Gauss-Jordan solve ----------------
__global__ void __launch_bounds__(256) k_solve(const float* __restrict__ partials,
        const int* __restrict__ counts, const float* __restrict__ pattern,
        float* __restrict__ params) {
    int bk = blockIdx.x;
    int t = threadIdx.x;
    __shared__ float M[64][67];
    __shared__ float ssum[CH];
    __shared__ float wv[CH];
    __shared__ float red[2];

    const float* pp = partials + (size_t)bk * NCHUNK * PSTRIDE;
    int cnt = counts[bk];
    float inv = 1.0f / fmaxf((float)cnt, 1.0f);
    if (t < CH) {
        float v = 0.f;
        #pragma unroll
        for (int ch = 0; ch < NCHUNK; ++ch) v += pp[(size_t)ch * PSTRIDE + 4096 + t];
        ssum[t] = v;
    }
    __syncthreads();
    for (int e = t; e < 4096; e += 256) {
        float v = 0.f;
        #pragma unroll
        for (int ch = 0; ch < NCHUNK; ++ch) v += pp[(size_t)ch * PSTRIDE + e];
        int c = e >> 6, d = e & 63;
        float cov = v * inv - (ssum[c] * inv) * (ssum[d] * inv);
        if (c == d) cov += EPSV;
        M[c][d] = cov;
    }
    if (t < CH) M[t][64] = pattern[t];
    __syncthreads();

    // Gauss-Jordan, one barrier per column
    int r = t >> 2, q = t & 3;
    for (int j = 0; j < 64; ++j) {
        float f = M[r][j] / M[j][j];
        if (r != j) {
            #pragma unroll 4
            for (int d = j + 1 + q; d <= 64; d += 4)
                M[r][d] -= f * M[j][d];
        }
        __syncthreads();
    }
    if (t < CH) wv[t] = M[t][64] / M[t][t];
    __syncthreads();

    if (t < CH) {
        float wvt = wv[t];
        float dp = pattern[t] * wvt;
        float bias = (ssum[t] * inv) * wvt;
        #pragma unroll
        for (int o = 32; o > 0; o >>= 1) {
            dp += __shfl_xor(dp, o);
            bias += __shfl_xor(bias, o);
        }
        if (t == 0) {
            float denom = sqrtf(dp);
            float valid = (cnt >= MINSZ) ? 1.0f : 0.0f;
            float scale = (denom > 0.f) ? (valid / denom) : 0.0f;
            red[0] = scale;
            red[1] = bias * scale;
        }
    }
    __syncthreads();
    if (t < CH) params[bk*66 + t] = wv[t] * red[0];
    if (t == 0) params[bk*66 + 64] = red[1];
    if (t == 1) params[bk*66 + 65] = 0.f;
}

// ---------------- K6: fused per-pixel score ----------------
__global__ void k_score(const float* __restrict__ x, const int* __restrict__ seg,
                        const float* __restrict__ params, float* __restrict__ out) {
    __shared__ float pw[NCLS][66];
    int t = threadIdx.x;
    int base = blockIdx.x * 256;
    int b = base / NPIX;
    for (int e = t; e < NCLS*66; e += 256)
        ((float*)pw)[e] = params[b*NCLS*66 + e];
    __syncthreads();

    int k = seg[base + t];
    int n = (base % NPIX) + t;
    const float* xb = x + (size_t)b * CH * NPIX + n;
    float a0 = 0.f, a1 = 0.f, a2 = 0.f, a3 = 0.f;
    #pragma unroll
    for (int c = 0; c < CH; c += 4) {
        a0 += xb[(size_t)(c+0) * NPIX] * pw[k][c+0];
        a1 += xb[(size_t)(c+1) * NPIX] * pw[k][c+1];
        a2 += xb[(size_t)(c+2) * NPIX] * pw[k][c+2];
        a3 += xb[(size_t)(c+3) * NPIX] * pw[k][c+3];
    }
    out[base + t] = (a0 + a1) + (a2 + a3) - pw[k][64];
}

// ---------------- launch ----------------
extern "C" void kernel_launch(void* const* d_in, const int* in_sizes, int n_in,
                              void* d_out, int out_size, void* d_ws, size_t ws_size,
                              hipStream_t stream) {
    const float* x       = (const float*)d_in[0];   // (B,C,H,W) fp32
    const float* pattern = (const float*)d_in[1];   // (C,) fp32
    const int*   seg     = (const int*)d_in[2];     // (B,H,W) int32
    float* out = (float*)d_out;

    unsigned short* gathered = (unsigned short*)d_ws;                  // B*N*CH bf16
    float* partials = (float*)(gathered + (size_t)BATCH * NPIX * CH);  // B*K*NCHUNK*PSTRIDE
    float* params   = partials + (size_t)BATCH * NCLS * NCHUNK * PSTRIDE; // B*K*66
    int* hist      = (int*)(params + BATCH * NCLS * 66);               // NBLK*NCLS
    int* blockbase = hist + NBLK * NCLS;                               // NBLK*NCLS
    int* counts    = blockbase + NBLK * NCLS;                          // B*K
    int* offsets   = counts + BATCH * NCLS;                            // B*K

    k_hist   <<<NBLK,               256, 0, stream>>>(seg, hist);
    k_scanall<<<BATCH*NCLS,         256, 0, stream>>>(hist, counts, blockbase, offsets);
    k_scatter<<<NBLK,               256, 0, stream>>>(x, seg, blockbase, gathered);
    k_gemm   <<<BATCH*NCLS*NCHUNK,  256, 0, stream>>>(gathered, counts, offsets, partials);
    k_solve  <<<BATCH*NCLS,         256, 0, stream>>>(partials, counts, pattern, params);
    k_score  <<<NBLK,               256, 0, stream>>>(x, seg, params, out);
}